// Round 10
// baseline (580.681 us; speedup 1.0000x reference)
//
#include <hip/hip_runtime.h>
#include <hip/hip_bf16.h>

#define HID 128

using bf16x8 = __attribute__((ext_vector_type(8))) short;
using f32x4  = __attribute__((ext_vector_type(4))) float;

__device__ inline float bf2f(unsigned int u16) {
    union { float f; unsigned int i; } v; v.i = u16 << 16; return v.f;
}
__device__ inline unsigned short f2bf(float f) {
    __hip_bfloat16 h = __float2bfloat16(f);        // RNE
    return *reinterpret_cast<unsigned short*>(&h);
}

// ---------------- CSR build ----------------

__global__ void zero_i32(int* __restrict__ p, int n) {
    int i = blockIdx.x * blockDim.x + threadIdx.x;
    if (i < n) p[i] = 0;
}

__global__ void count_deg(const int* __restrict__ dst, int* __restrict__ deg, int E) {
    int e = blockIdx.x * blockDim.x + threadIdx.x;
    if (e < E) atomicAdd(&deg[dst[e]], 1);
}

__global__ __launch_bounds__(256) void block_sums(const int* __restrict__ deg,
                                                  int* __restrict__ bsum, int n) {
    __shared__ int red[256];
    int t = threadIdx.x;
    int i = blockIdx.x * 256 + t;
    red[t] = (i < n) ? deg[i] : 0;
    __syncthreads();
    for (int off = 128; off > 0; off >>= 1) {
        if (t < off) red[t] += red[t + off];
        __syncthreads();
    }
    if (t == 0) bsum[blockIdx.x] = red[0];
}

__global__ __launch_bounds__(1024) void scan_bsums(const int* __restrict__ bsum,
                                                   int* __restrict__ bstart, int nb) {
    __shared__ int s[1024];
    int t = threadIdx.x;
    s[t] = (t < nb) ? bsum[t] : 0;
    __syncthreads();
    for (int off = 1; off < 1024; off <<= 1) {
        int v = (t >= off) ? s[t - off] : 0;
        __syncthreads();
        s[t] += v;
        __syncthreads();
    }
    if (t < nb) bstart[t] = (t == 0) ? 0 : s[t - 1];
}

__global__ __launch_bounds__(256) void scan_within(const int* __restrict__ deg,
                                                   const int* __restrict__ bstart,
                                                   int* __restrict__ row_ptr,
                                                   int* __restrict__ pos, int n) {
    __shared__ int s[256];
    int b = blockIdx.x, t = threadIdx.x;
    int i = b * 256 + t;
    int v = (i < n) ? deg[i] : 0;
    s[t] = v;
    __syncthreads();
    for (int off = 1; off < 256; off <<= 1) {
        int u = (t >= off) ? s[t - off] : 0;
        __syncthreads();
        s[t] += u;
        __syncthreads();
    }
    if (i < n) {
        int excl = bstart[b] + s[t] - v;
        row_ptr[i] = excl;
        pos[i] = excl;
        if (i == n - 1) row_ptr[n] = bstart[b] + s[t];
    }
}

__global__ void fill_csr(const int* __restrict__ src, const int* __restrict__ dst,
                         int* __restrict__ pos, int* __restrict__ csr_src, int E) {
    int e = blockIdx.x * blockDim.x + threadIdx.x;
    if (e < E) {
        int p = atomicAdd(&pos[dst[e]], 1);
        csr_src[p] = src[e];
    }
}

__global__ void graph_starts(const int* __restrict__ batch, int* __restrict__ gstart,
                             int n, int G) {
    int g = blockIdx.x * blockDim.x + threadIdx.x;
    if (g > G) return;
    int lo = 0, hi = n;
    while (lo < hi) { int m = (lo + hi) >> 1; if (batch[m] < g) lo = m + 1; else hi = m; }
    gstart[g] = lo;
}

// ---------------- conversions ----------------

__global__ void f32_to_bf16_vec(const float* __restrict__ in,
                                unsigned short* __restrict__ out, int n8) {
    int i = blockIdx.x * blockDim.x + threadIdx.x;
    if (i >= n8) return;
    const float4* in4 = (const float4*)in;
    float4 a = in4[i * 2], b = in4[i * 2 + 1];
    uint4 o;
    o.x = f2bf(a.x) | ((unsigned)f2bf(a.y) << 16);
    o.y = f2bf(a.z) | ((unsigned)f2bf(a.w) << 16);
    o.z = f2bf(b.x) | ((unsigned)f2bf(b.y) << 16);
    o.w = f2bf(b.z) | ((unsigned)f2bf(b.w) << 16);
    ((uint4*)out)[i] = o;
}

// W[mat][k][c] fp32 -> Wt[mat][c][k] bf16
__global__ void transpose_kc(const float* __restrict__ W, unsigned short* __restrict__ Wt,
                             int K, int C, int total) {
    int tid = blockIdx.x * blockDim.x + threadIdx.x;
    if (tid >= total) return;
    int kc = K * C;
    int mat = tid / kc;
    int rem = tid - mat * kc;
    int c = rem / K;
    int k = rem - c * K;
    Wt[tid] = f2bf(W[(size_t)mat * kc + (size_t)k * C + c]);
}

// ---------------- fused GIN layer (gather + MLP), compact h source ----------------
// block = 256 thr = 4 waves, 16 node rows.
// Gather reads COMPACT hprev[N][128] (dense 12.8 MB working set);
// 16 lanes/node = 2 subs x 8 chunk-lanes; each sub walks its edge parity with
// unroll 4 (8 uint4 loads in flight); pair-combine via shfl_xor(8).
// GEMM1 -> relu -> tt; GEMM2 -> +b2 [,+xres bf16] -> writes compact hnext AND emb slice.
template <bool ODD>
__global__ __launch_bounds__(256) void fused_layer(const unsigned short* __restrict__ hprev,
                                                   const int* __restrict__ row_ptr,
                                                   const int* __restrict__ csr_src,
                                                   const unsigned short* __restrict__ Wt1,
                                                   const float* __restrict__ b1,
                                                   const unsigned short* __restrict__ Wt2,
                                                   const float* __restrict__ b2,
                                                   unsigned short* __restrict__ xres,
                                                   unsigned short* __restrict__ hnext,
                                                   unsigned short* __restrict__ emb_slice,
                                                   int out_stride, int N) {
    __shared__ __align__(16) char zt[16 * 256];    // z tile bf16, XOR-swizzled
    __shared__ __align__(16) char tt[16 * 256];    // t tile bf16, XOR-swizzled
    int t = threadIdx.x;
    int rowbase = blockIdx.x * 16;

    // ---- gather (edge-split across sub pairs, unroll 4) ----
    {
        int nl = t >> 4;                 // local node 0..15
        int sub = (t >> 3) & 1;          // edge-parity half
        int lane8 = t & 7;               // chunk lane (chains lane8, lane8+8)
        int node = rowbase + nl;
        const uint4* h4 = (const uint4*)hprev;
        float sa0=0,sa1=0,sa2=0,sa3=0,sa4=0,sa5=0,sa6=0,sa7=0;
        float sb0=0,sb1=0,sb2=0,sb3=0,sb4=0,sb5=0,sb6=0,sb7=0;
        if (node < N) {
            if (sub == 0) {
                size_t base = (size_t)node * 16;
                uint4 u0 = h4[base + lane8];
                uint4 u1 = h4[base + lane8 + 8];
                sa0 = bf2f(u0.x & 0xffff); sa1 = bf2f(u0.x >> 16);
                sa2 = bf2f(u0.y & 0xffff); sa3 = bf2f(u0.y >> 16);
                sa4 = bf2f(u0.z & 0xffff); sa5 = bf2f(u0.z >> 16);
                sa6 = bf2f(u0.w & 0xffff); sa7 = bf2f(u0.w >> 16);
                sb0 = bf2f(u1.x & 0xffff); sb1 = bf2f(u1.x >> 16);
                sb2 = bf2f(u1.y & 0xffff); sb3 = bf2f(u1.y >> 16);
                sb4 = bf2f(u1.z & 0xffff); sb5 = bf2f(u1.z >> 16);
                sb6 = bf2f(u1.w & 0xffff); sb7 = bf2f(u1.w >> 16);
            }
            int e0 = row_ptr[node], e1 = row_ptr[node + 1];
            int e = e0 + sub;
#define ACC_ROW(v0, v1)                                                   \
            sa0 += bf2f(v0.x & 0xffff); sa1 += bf2f(v0.x >> 16);          \
            sa2 += bf2f(v0.y & 0xffff); sa3 += bf2f(v0.y >> 16);          \
            sa4 += bf2f(v0.z & 0xffff); sa5 += bf2f(v0.z >> 16);          \
            sa6 += bf2f(v0.w & 0xffff); sa7 += bf2f(v0.w >> 16);          \
            sb0 += bf2f(v1.x & 0xffff); sb1 += bf2f(v1.x >> 16);          \
            sb2 += bf2f(v1.y & 0xffff); sb3 += bf2f(v1.y >> 16);          \
            sb4 += bf2f(v1.z & 0xffff); sb5 += bf2f(v1.z >> 16);          \
            sb6 += bf2f(v1.w & 0xffff); sb7 += bf2f(v1.w >> 16);
            for (; e + 6 < e1; e += 8) {             // 4 edges/iter, 8 loads in flight
                size_t p0 = (size_t)csr_src[e] * 16;
                size_t p1 = (size_t)csr_src[e + 2] * 16;
                size_t p2 = (size_t)csr_src[e + 4] * 16;
                size_t p3 = (size_t)csr_src[e + 6] * 16;
                uint4 a0 = h4[p0 + lane8], a1 = h4[p0 + lane8 + 8];
                uint4 c0 = h4[p1 + lane8], c1 = h4[p1 + lane8 + 8];
                uint4 d0 = h4[p2 + lane8], d1 = h4[p2 + lane8 + 8];
                uint4 f0 = h4[p3 + lane8], f1 = h4[p3 + lane8 + 8];
                ACC_ROW(a0, a1)
                ACC_ROW(c0, c1)
                ACC_ROW(d0, d1)
                ACC_ROW(f0, f1)
            }
            for (; e < e1; e += 2) {
                size_t p0 = (size_t)csr_src[e] * 16;
                uint4 a0 = h4[p0 + lane8], a1 = h4[p0 + lane8 + 8];
                ACC_ROW(a0, a1)
            }
#undef ACC_ROW
        }
        // pair-combine (t <-> t^8): both subs end with full sums
        sa0 += __shfl_xor(sa0, 8); sa1 += __shfl_xor(sa1, 8);
        sa2 += __shfl_xor(sa2, 8); sa3 += __shfl_xor(sa3, 8);
        sa4 += __shfl_xor(sa4, 8); sa5 += __shfl_xor(sa5, 8);
        sa6 += __shfl_xor(sa6, 8); sa7 += __shfl_xor(sa7, 8);
        sb0 += __shfl_xor(sb0, 8); sb1 += __shfl_xor(sb1, 8);
        sb2 += __shfl_xor(sb2, 8); sb3 += __shfl_xor(sb3, 8);
        sb4 += __shfl_xor(sb4, 8); sb5 += __shfl_xor(sb5, 8);
        sb6 += __shfl_xor(sb6, 8); sb7 += __shfl_xor(sb7, 8);
        // sub0 writes chain lane8 (sa), sub1 writes chain lane8+8 (sb)
        uint4 o;
        if (sub == 0) {
            o.x = f2bf(sa0) | ((unsigned)f2bf(sa1) << 16);
            o.y = f2bf(sa2) | ((unsigned)f2bf(sa3) << 16);
            o.z = f2bf(sa4) | ((unsigned)f2bf(sa5) << 16);
            o.w = f2bf(sa6) | ((unsigned)f2bf(sa7) << 16);
        } else {
            o.x = f2bf(sb0) | ((unsigned)f2bf(sb1) << 16);
            o.y = f2bf(sb2) | ((unsigned)f2bf(sb3) << 16);
            o.z = f2bf(sb4) | ((unsigned)f2bf(sb5) << 16);
            o.w = f2bf(sb6) | ((unsigned)f2bf(sb7) << 16);
        }
        int chunk = lane8 + sub * 8;
        *(uint4*)(zt + nl * 256 + ((chunk * 16) ^ ((nl & 7) << 4))) = o;
    }
    __syncthreads();

    int wave = t >> 6, lane = t & 63, l15 = lane & 15, l4 = lane >> 4;
    int colbase = wave * 32;

    f32x4 acc[2];
#pragma unroll
    for (int ct = 0; ct < 2; ct++) acc[ct] = (f32x4){0.f, 0.f, 0.f, 0.f};

    // ---- GEMM1: A from zt, wave's 32 cols ----
#pragma unroll
    for (int kk = 0; kk < 4; kk++) {
        int k0 = kk * 32 + l4 * 8;
        bf16x8 a0 = *(const bf16x8*)(zt + l15 * 256 + ((k0 * 2) ^ ((l15 & 7) << 4)));
#pragma unroll
        for (int ct = 0; ct < 2; ct++) {
            bf16x8 b = *(const bf16x8*)&Wt1[(size_t)(colbase + ct * 16 + l15) * HID + k0];
            acc[ct] = __builtin_amdgcn_mfma_f32_16x16x32_bf16(a0, b, acc[ct], 0, 0, 0);
        }
    }

    // ---- epilogue1: relu(acc+b1) -> tt ----
#pragma unroll
    for (int ct = 0; ct < 2; ct++) {
        int col = colbase + ct * 16 + l15;
        float bc = b1[col];
#pragma unroll
        for (int j = 0; j < 4; j++) {
            int r = l4 * 4 + j;                     // rows 0..15
            float v = fmaxf(acc[ct][j] + bc, 0.f);
            *(unsigned short*)(tt + r * 256 + ((col * 2) ^ ((r & 7) << 4))) = f2bf(v);
        }
    }
    __syncthreads();

    // ---- GEMM2: A from full tt (K=128), wave's 32 output cols ----
#pragma unroll
    for (int ct = 0; ct < 2; ct++) acc[ct] = (f32x4){0.f, 0.f, 0.f, 0.f};
#pragma unroll
    for (int kk = 0; kk < 4; kk++) {
        int k0 = kk * 32 + l4 * 8;
        bf16x8 a0 = *(const bf16x8*)(tt + l15 * 256 + ((k0 * 2) ^ ((l15 & 7) << 4)));
#pragma unroll
        for (int ct = 0; ct < 2; ct++) {
            bf16x8 b = *(const bf16x8*)&Wt2[(size_t)(colbase + ct * 16 + l15) * HID + k0];
            acc[ct] = __builtin_amdgcn_mfma_f32_16x16x32_bf16(a0, b, acc[ct], 0, 0, 0);
        }
    }

    // ---- epilogue2: +b2 [,+xres bf16]; write compact hnext + emb slice ----
#pragma unroll
    for (int ct = 0; ct < 2; ct++) {
        int col = colbase + ct * 16 + l15;
        float bc = b2[col];
#pragma unroll
        for (int j = 0; j < 4; j++) {
            int r = l4 * 4 + j;
            int rg = rowbase + r;
            if (rg < N) {
                float v = acc[ct][j] + bc;
                if (ODD) {
                    v += bf2f(xres[(size_t)rg * HID + col]);
                    xres[(size_t)rg * HID + col] = f2bf(v);
                }
                unsigned short hv = f2bf(fmaxf(v, 0.f));
                hnext[(size_t)rg * HID + col] = hv;
                emb_slice[(size_t)rg * out_stride + col] = hv;
            }
        }
    }
}

// ---------------- pre linear (MFMA; writes emb slice 0 + compact h + xres bf16) ----------------
__global__ __launch_bounds__(256) void linear_pre(const unsigned short* __restrict__ in,
                                                  const unsigned short* __restrict__ Wt,
                                                  const float* __restrict__ bias,
                                                  unsigned short* __restrict__ emb0,
                                                  int out_stride,
                                                  unsigned short* __restrict__ hcompact,
                                                  unsigned short* __restrict__ pre_out, int M) {
    int tid = threadIdx.x;
    int wave = tid >> 6, lane = tid & 63;
    int l15 = lane & 15, l4 = lane >> 4;
    int rowbase = blockIdx.x * 64 + wave * 16;
    f32x4 acc[8];
#pragma unroll
    for (int ct = 0; ct < 8; ct++) acc[ct] = (f32x4){0.f, 0.f, 0.f, 0.f};
    int r0 = min(rowbase + l15, M - 1);
#pragma unroll
    for (int kk = 0; kk < 4; kk++) {
        int k0 = kk * 32 + l4 * 8;
        bf16x8 a0 = *(const bf16x8*)&in[(size_t)r0 * HID + k0];
#pragma unroll
        for (int ct = 0; ct < 8; ct++) {
            bf16x8 b = *(const bf16x8*)&Wt[(size_t)(ct * 16 + l15) * HID + k0];
            acc[ct] = __builtin_amdgcn_mfma_f32_16x16x32_bf16(a0, b, acc[ct], 0, 0, 0);
        }
    }
#pragma unroll
    for (int ct = 0; ct < 8; ct++) {
        int col = ct * 16 + l15;
        float bc = bias[col];
#pragma unroll
        for (int j = 0; j < 4; j++) {
            int r = rowbase + l4 * 4 + j;
            if (r < M) {
                float v = acc[ct][j] + bc;
                unsigned short bv = f2bf(v);
                pre_out[(size_t)r * HID + col] = bv;          // xres bf16
                hcompact[(size_t)r * HID + col] = bv;         // compact h (layer-0 gather src)
                emb0[(size_t)r * out_stride + col] = bv;      // emb slice 0
            }
        }
    }
}

// ---------------- pooling over full emb, 2-level deterministic ----------------
__global__ __launch_bounds__(128) void pool_all(const unsigned short* __restrict__ emb,
                                                const int* __restrict__ gstart,
                                                float* __restrict__ part, int EMB) {
    int g = blockIdx.x >> 3, sub = blockIdx.x & 7;
    int t = threadIdx.x;
    if (t >= 112) return;
    const uint4* e4 = (const uint4*)emb;     // row stride EMB/8 = 112 uint4
    int row_u4 = EMB / 8;
    int n0 = gstart[g], n1 = gstart[g + 1];
    float s[8] = {0.f, 0.f, 0.f, 0.f, 0.f, 0.f, 0.f, 0.f};
    for (int n = n0 + sub; n < n1; n += 8) {
        uint4 v = e4[(size_t)n * row_u4 + t];
        s[0] += bf2f(v.x & 0xffff); s[1] += bf2f(v.x >> 16);
        s[2] += bf2f(v.y & 0xffff); s[3] += bf2f(v.y >> 16);
        s[4] += bf2f(v.z & 0xffff); s[5] += bf2f(v.z >> 16);
        s[6] += bf2f(v.w & 0xffff); s[7] += bf2f(v.w >> 16);
    }
    float4* p4 = (float4*)&part[(size_t)blockIdx.x * EMB + t * 8];
    p4[0] = (float4){s[0], s[1], s[2], s[3]};
    p4[1] = (float4){s[4], s[5], s[6], s[7]};
}

__global__ __launch_bounds__(128) void pool_fin(const float* __restrict__ part,
                                                unsigned short* __restrict__ pooled,
                                                int EMB) {
    int idx = blockIdx.x * 128 + threadIdx.x;   // over G*EMB
    int g = idx / EMB, c = idx - g * EMB;
    float s = 0.f;
#pragma unroll
    for (int sub = 0; sub < 8; sub++)
        s += part[(size_t)(g * 8 + sub) * EMB + c];
    pooled[idx] = f2bf(s);
}

// ---------------- post MLP via MFMA ----------------
__global__ __launch_bounds__(256) void post_mfma(const unsigned short* __restrict__ pooled,
                                                 const unsigned short* __restrict__ w1t,
                                                 const float* __restrict__ b1,
                                                 const unsigned short* __restrict__ w2t,
                                                 const float* __restrict__ b2,
                                                 float* __restrict__ out, int EMB) {
    __shared__ __align__(16) char lds[128 * 256];
    int t = threadIdx.x;
    int wave = t >> 6, lane = t & 63, l15 = lane & 15, l4 = lane >> 4;
    int wrow = wave * 32;
    f32x4 acc[2][8];
#pragma unroll
    for (int rt = 0; rt < 2; rt++)
#pragma unroll
        for (int ct = 0; ct < 8; ct++) acc[rt][ct] = (f32x4){0.f, 0.f, 0.f, 0.f};
    int r0 = wrow + l15, r1 = r0 + 16;
#pragma unroll 4
    for (int kk = 0; kk < EMB / 32; kk++) {
        int k0 = kk * 32 + l4 * 8;
        bf16x8 a0 = *(const bf16x8*)&pooled[(size_t)r0 * EMB + k0];
        bf16x8 a1 = *(const bf16x8*)&pooled[(size_t)r1 * EMB + k0];
#pragma unroll
        for (int ct = 0; ct < 8; ct++) {
            bf16x8 b = *(const bf16x8*)&w1t[(size_t)(ct * 16 + l15) * EMB + k0];
            acc[0][ct] = __builtin_amdgcn_mfma_f32_16x16x32_bf16(a0, b, acc[0][ct], 0, 0, 0);
            acc[1][ct] = __builtin_amdgcn_mfma_f32_16x16x32_bf16(a1, b, acc[1][ct], 0, 0, 0);
        }
    }
#pragma unroll
    for (int ct = 0; ct < 8; ct++) {
        int col = ct * 16 + l15;
        float bc = b1[col];
#pragma unroll
        for (int rt = 0; rt < 2; rt++)
#pragma unroll
            for (int j = 0; j < 4; j++) {
                int r = wrow + rt * 16 + l4 * 4 + j;
                float v = fmaxf(acc[rt][ct][j] + bc, 0.f);
                *(unsigned short*)(lds + r * 256 + ((col * 2) ^ ((r & 7) << 4))) = f2bf(v);
            }
    }
    __syncthreads();
#pragma unroll
    for (int rt = 0; rt < 2; rt++)
#pragma unroll
        for (int ct = 0; ct < 8; ct++) acc[rt][ct] = (f32x4){0.f, 0.f, 0.f, 0.f};
#pragma unroll
    for (int kk = 0; kk < 4; kk++) {
        int k0 = kk * 32 + l4 * 8;
        bf16x8 a0 = *(const bf16x8*)(lds + r0 * 256 + ((k0 * 2) ^ ((r0 & 7) << 4)));
        bf16x8 a1 = *(const bf16x8*)(lds + r1 * 256 + ((k0 * 2) ^ ((r1 & 7) << 4)));
#pragma unroll
        for (int ct = 0; ct < 8; ct++) {
            bf16x8 b = *(const bf16x8*)&w2t[(size_t)(ct * 16 + l15) * HID + k0];
            acc[0][ct] = __builtin_amdgcn_mfma_f32_16x16x32_bf16(a0, b, acc[0][ct], 0, 0, 0);
            acc[1][ct] = __builtin_amdgcn_mfma_f32_16x16x32_bf16(a1, b, acc[1][ct], 0, 0, 0);
        }
    }
#pragma unroll
    for (int ct = 0; ct < 8; ct++) {
        int col = ct * 16 + l15;
        float bc = b2[col];
#pragma unroll
        for (int rt = 0; rt < 2; rt++)
#pragma unroll
            for (int j = 0; j < 4; j++) {
                int r = wrow + rt * 16 + l4 * 4 + j;
                out[(size_t)r * HID + col] = acc[rt][ct][j] + bc;
            }
    }
}

// ---------------- launch ----------------

extern "C" void kernel_launch(void* const* d_in, const int* in_sizes, int n_in,
                              void* d_out, int out_size, void* d_ws, size_t ws_size,
                              hipStream_t stream) {
    const float* x       = (const float*)d_in[0];
    const int* edge_index= (const int*)d_in[1];
    const int* batch     = (const int*)d_in[2];
    const float* pre_w   = (const float*)d_in[3];
    const float* pre_b   = (const float*)d_in[4];
    const float* conv_w1 = (const float*)d_in[5];
    const float* conv_b1 = (const float*)d_in[6];
    const float* conv_w2 = (const float*)d_in[7];
    const float* conv_b2 = (const float*)d_in[8];
    const float* post_w1 = (const float*)d_in[9];
    const float* post_b1 = (const float*)d_in[10];
    const float* post_w2 = (const float*)d_in[11];
    const float* post_b2 = (const float*)d_in[12];
    float* outp = (float*)d_out;

    int N = in_sizes[0] / HID;
    int E = in_sizes[1] / 2;
    int L = in_sizes[5] / (HID * HID);
    int G = out_size / HID;
    int EMB = (L + 1) * HID;

    const int* src = edge_index;
    const int* dst = edge_index + E;

    char* w = (char*)d_ws;
    auto alloc = [&](size_t bytes) -> char* {
        char* p = w;
        w += (bytes + 255) & ~(size_t)255;
        return p;
    };
    unsigned short* emb   = (unsigned short*)alloc((size_t)N * EMB * 2);     // all layer embeddings
    unsigned short* hA    = (unsigned short*)alloc((size_t)N * HID * 2);     // compact h double-buffer
    unsigned short* hB    = (unsigned short*)alloc((size_t)N * HID * 2);
    unsigned short* x_bf  = (unsigned short*)alloc((size_t)N * HID * 2);
    unsigned short* xres  = (unsigned short*)alloc((size_t)N * HID * 2);     // bf16 residual
    float* part   = (float*)alloc((size_t)G * 8 * EMB * 4);
    unsigned short* pooled = (unsigned short*)alloc((size_t)G * EMB * 2);
    unsigned short* Wt_pre = (unsigned short*)alloc((size_t)HID * HID * 2);
    unsigned short* Wt_c1  = (unsigned short*)alloc((size_t)L * HID * HID * 2);
    unsigned short* Wt_c2  = (unsigned short*)alloc((size_t)L * HID * HID * 2);
    unsigned short* w1t    = (unsigned short*)alloc((size_t)EMB * HID * 2);
    unsigned short* w2t    = (unsigned short*)alloc((size_t)HID * HID * 2);
    int* deg      = (int*)alloc((size_t)(N + 1) * 4);
    int* row_ptr  = (int*)alloc((size_t)(N + 1) * 4);
    int* pos      = (int*)alloc((size_t)(N + 1) * 4);
    int* bsum     = (int*)alloc((size_t)1024 * 4);
    int* bstart   = (int*)alloc((size_t)1024 * 4);
    int* csr_src  = (int*)alloc((size_t)E * 4);
    int* gstart   = (int*)alloc((size_t)(G + 1) * 4);
    (void)ws_size; (void)n_in;

    int eb = (E + 255) / 256;
    int nb = (N + 255) / 256;

    // CSR by dst
    zero_i32<<<nb, 256, 0, stream>>>(deg, N);
    count_deg<<<eb, 256, 0, stream>>>(dst, deg, E);
    block_sums<<<nb, 256, 0, stream>>>(deg, bsum, N);
    scan_bsums<<<1, 1024, 0, stream>>>(bsum, bstart, nb);
    scan_within<<<nb, 256, 0, stream>>>(deg, bstart, row_ptr, pos, N);
    fill_csr<<<eb, 256, 0, stream>>>(src, dst, pos, csr_src, E);
    graph_starts<<<1, 256, 0, stream>>>(batch, gstart, N, G);

    // conversions / transposes
    f32_to_bf16_vec<<<(N * HID / 8 + 255) / 256, 256, 0, stream>>>(x, x_bf, N * HID / 8);
    transpose_kc<<<(HID * HID + 255) / 256, 256, 0, stream>>>(pre_w, Wt_pre, HID, HID, HID * HID);
    transpose_kc<<<(L * HID * HID + 255) / 256, 256, 0, stream>>>(conv_w1, Wt_c1, HID, HID, L * HID * HID);
    transpose_kc<<<(L * HID * HID + 255) / 256, 256, 0, stream>>>(conv_w2, Wt_c2, HID, HID, L * HID * HID);
    transpose_kc<<<(EMB * HID + 255) / 256, 256, 0, stream>>>(post_w1, w1t, EMB, HID, EMB * HID);
    transpose_kc<<<(HID * HID + 255) / 256, 256, 0, stream>>>(post_w2, w2t, HID, HID, HID * HID);

    int gb64 = (N + 63) / 64;
    int gb16 = (N + 15) / 16;

    // pre linear: emb slice0 + compact hA + xres
    linear_pre<<<gb64, 256, 0, stream>>>(x_bf, Wt_pre, pre_b, emb, EMB, hA, xres, N);

    unsigned short* hcur = hA;
    unsigned short* hnxt = hB;
    for (int i = 0; i < L; i++) {
        unsigned short* slice_out = emb + (size_t)(i + 1) * HID;
        if (i & 1) {
            fused_layer<true><<<gb16, 256, 0, stream>>>(
                hcur, row_ptr, csr_src,
                Wt_c1 + (size_t)i * HID * HID, conv_b1 + i * HID,
                Wt_c2 + (size_t)i * HID * HID, conv_b2 + i * HID,
                xres, hnxt, slice_out, EMB, N);
        } else {
            fused_layer<false><<<gb16, 256, 0, stream>>>(
                hcur, row_ptr, csr_src,
                Wt_c1 + (size_t)i * HID * HID, conv_b1 + i * HID,
                Wt_c2 + (size_t)i * HID * HID, conv_b2 + i * HID,
                xres, hnxt, slice_out, EMB, N);
        }
        unsigned short* tmp = hcur; hcur = hnxt; hnxt = tmp;
    }

    pool_all<<<G * 8, 128, 0, stream>>>(emb, gstart, part, EMB);
    pool_fin<<<(G * EMB) / 128, 128, 0, stream>>>(part, pooled, EMB);
    post_mfma<<<1, 256, 0, stream>>>(pooled, w1t, post_b1, w2t, post_b2, outp, EMB);
}

// Round 11
// 535.054 us; speedup vs baseline: 1.0853x; 1.0853x over previous
//
#include <hip/hip_runtime.h>
#include <hip/hip_bf16.h>

#define HID 128

using bf16x8 = __attribute__((ext_vector_type(8))) short;
using f32x4  = __attribute__((ext_vector_type(4))) float;

__device__ inline float bf2f(unsigned int u16) {
    union { float f; unsigned int i; } v; v.i = u16 << 16; return v.f;
}
__device__ inline unsigned short f2bf(float f) {
    __hip_bfloat16 h = __float2bfloat16(f);        // RNE
    return *reinterpret_cast<unsigned short*>(&h);
}

// ---------------- CSR build ----------------

__global__ void zero_i32(int* __restrict__ p, int n) {
    int i = blockIdx.x * blockDim.x + threadIdx.x;
    if (i < n) p[i] = 0;
}

__global__ void count_deg(const int* __restrict__ dst, int* __restrict__ deg, int E) {
    int e = blockIdx.x * blockDim.x + threadIdx.x;
    if (e < E) atomicAdd(&deg[dst[e]], 1);
}

__global__ __launch_bounds__(256) void block_sums(const int* __restrict__ deg,
                                                  int* __restrict__ bsum, int n) {
    __shared__ int red[256];
    int t = threadIdx.x;
    int i = blockIdx.x * 256 + t;
    red[t] = (i < n) ? deg[i] : 0;
    __syncthreads();
    for (int off = 128; off > 0; off >>= 1) {
        if (t < off) red[t] += red[t + off];
        __syncthreads();
    }
    if (t == 0) bsum[blockIdx.x] = red[0];
}

__global__ __launch_bounds__(1024) void scan_bsums(const int* __restrict__ bsum,
                                                   int* __restrict__ bstart, int nb) {
    __shared__ int s[1024];
    int t = threadIdx.x;
    s[t] = (t < nb) ? bsum[t] : 0;
    __syncthreads();
    for (int off = 1; off < 1024; off <<= 1) {
        int v = (t >= off) ? s[t - off] : 0;
        __syncthreads();
        s[t] += v;
        __syncthreads();
    }
    if (t < nb) bstart[t] = (t == 0) ? 0 : s[t - 1];
}

__global__ __launch_bounds__(256) void scan_within(const int* __restrict__ deg,
                                                   const int* __restrict__ bstart,
                                                   int* __restrict__ row_ptr,
                                                   int* __restrict__ pos, int n) {
    __shared__ int s[256];
    int b = blockIdx.x, t = threadIdx.x;
    int i = b * 256 + t;
    int v = (i < n) ? deg[i] : 0;
    s[t] = v;
    __syncthreads();
    for (int off = 1; off < 256; off <<= 1) {
        int u = (t >= off) ? s[t - off] : 0;
        __syncthreads();
        s[t] += u;
        __syncthreads();
    }
    if (i < n) {
        int excl = bstart[b] + s[t] - v;
        row_ptr[i] = excl;
        pos[i] = excl;
        if (i == n - 1) row_ptr[n] = bstart[b] + s[t];
    }
}

__global__ void fill_csr(const int* __restrict__ src, const int* __restrict__ dst,
                         int* __restrict__ pos, int* __restrict__ csr_src, int E) {
    int e = blockIdx.x * blockDim.x + threadIdx.x;
    if (e < E) {
        int p = atomicAdd(&pos[dst[e]], 1);
        csr_src[p] = src[e];
    }
}

__global__ void graph_starts(const int* __restrict__ batch, int* __restrict__ gstart,
                             int n, int G) {
    int g = blockIdx.x * blockDim.x + threadIdx.x;
    if (g > G) return;
    int lo = 0, hi = n;
    while (lo < hi) { int m = (lo + hi) >> 1; if (batch[m] < g) lo = m + 1; else hi = m; }
    gstart[g] = lo;
}

// ---------------- conversions ----------------

__global__ void f32_to_bf16_vec(const float* __restrict__ in,
                                unsigned short* __restrict__ out, int n8) {
    int i = blockIdx.x * blockDim.x + threadIdx.x;
    if (i >= n8) return;
    const float4* in4 = (const float4*)in;
    float4 a = in4[i * 2], b = in4[i * 2 + 1];
    uint4 o;
    o.x = f2bf(a.x) | ((unsigned)f2bf(a.y) << 16);
    o.y = f2bf(a.z) | ((unsigned)f2bf(a.w) << 16);
    o.z = f2bf(b.x) | ((unsigned)f2bf(b.y) << 16);
    o.w = f2bf(b.z) | ((unsigned)f2bf(b.w) << 16);
    ((uint4*)out)[i] = o;
}

// W[mat][k][c] fp32 -> Wt[mat][c][k] bf16
__global__ void transpose_kc(const float* __restrict__ W, unsigned short* __restrict__ Wt,
                             int K, int C, int total) {
    int tid = blockIdx.x * blockDim.x + threadIdx.x;
    if (tid >= total) return;
    int kc = K * C;
    int mat = tid / kc;
    int rem = tid - mat * kc;
    int c = rem / K;
    int k = rem - c * K;
    Wt[tid] = f2bf(W[(size_t)mat * kc + (size_t)k * C + c]);
}

// ---------------- fused GIN layer (gather + MLP), 8-wave, 4-way edge-split ----------------
// block = 512 thr = 8 waves, 16 node rows.
// Gather: 32 lanes/node = 4 subs x 8 chunk-lanes; sub s walks edges e0+s, e0+s+4,...
//   (2 uint4 chains, unroll 2 -> 4 loads in flight); combine shfl_xor(8) + shfl_xor(16).
// GEMM1: wave w computes cols [w*16,w*16+16) from zt; relu -> tt.
// GEMM2: A from tt (K=128); +b2 [,+xres bf16]; emb slice = relu.
template <bool ODD>
__global__ __launch_bounds__(512) void fused_layer(const unsigned short* __restrict__ emb,
                                                   int slice_u4, int row_u4,
                                                   const int* __restrict__ row_ptr,
                                                   const int* __restrict__ csr_src,
                                                   const unsigned short* __restrict__ Wt1,
                                                   const float* __restrict__ b1,
                                                   const unsigned short* __restrict__ Wt2,
                                                   const float* __restrict__ b2,
                                                   unsigned short* __restrict__ xres,
                                                   unsigned short* __restrict__ h_out,
                                                   int out_stride, int N) {
    __shared__ __align__(16) char zt[16 * 256];    // z tile bf16, XOR-swizzled
    __shared__ __align__(16) char tt[16 * 256];    // t tile bf16, XOR-swizzled
    int t = threadIdx.x;
    int rowbase = blockIdx.x * 16;

    // ---- gather (4-way edge-split, unroll 2) ----
    {
        int nl = t >> 5;                 // local node 0..15
        int sub = (t >> 3) & 3;          // edge parity 0..3
        int lane8 = t & 7;               // chunk lane (chains lane8, lane8+8)
        int node = rowbase + nl;
        const uint4* h4 = (const uint4*)emb;
        float sa0=0,sa1=0,sa2=0,sa3=0,sa4=0,sa5=0,sa6=0,sa7=0;
        float sb0=0,sb1=0,sb2=0,sb3=0,sb4=0,sb5=0,sb6=0,sb7=0;
        if (node < N) {
            if (sub == 0) {
                size_t base = (size_t)node * row_u4 + slice_u4;
                uint4 u0 = h4[base + lane8];
                uint4 u1 = h4[base + lane8 + 8];
                sa0 = bf2f(u0.x & 0xffff); sa1 = bf2f(u0.x >> 16);
                sa2 = bf2f(u0.y & 0xffff); sa3 = bf2f(u0.y >> 16);
                sa4 = bf2f(u0.z & 0xffff); sa5 = bf2f(u0.z >> 16);
                sa6 = bf2f(u0.w & 0xffff); sa7 = bf2f(u0.w >> 16);
                sb0 = bf2f(u1.x & 0xffff); sb1 = bf2f(u1.x >> 16);
                sb2 = bf2f(u1.y & 0xffff); sb3 = bf2f(u1.y >> 16);
                sb4 = bf2f(u1.z & 0xffff); sb5 = bf2f(u1.z >> 16);
                sb6 = bf2f(u1.w & 0xffff); sb7 = bf2f(u1.w >> 16);
            }
            int e0 = row_ptr[node], e1 = row_ptr[node + 1];
            int e = e0 + sub;
#define ACC_ROW(v0, v1)                                                   \
            sa0 += bf2f(v0.x & 0xffff); sa1 += bf2f(v0.x >> 16);          \
            sa2 += bf2f(v0.y & 0xffff); sa3 += bf2f(v0.y >> 16);          \
            sa4 += bf2f(v0.z & 0xffff); sa5 += bf2f(v0.z >> 16);          \
            sa6 += bf2f(v0.w & 0xffff); sa7 += bf2f(v0.w >> 16);          \
            sb0 += bf2f(v1.x & 0xffff); sb1 += bf2f(v1.x >> 16);          \
            sb2 += bf2f(v1.y & 0xffff); sb3 += bf2f(v1.y >> 16);          \
            sb4 += bf2f(v1.z & 0xffff); sb5 += bf2f(v1.z >> 16);          \
            sb6 += bf2f(v1.w & 0xffff); sb7 += bf2f(v1.w >> 16);
            for (; e + 4 < e1; e += 8) {             // 2 edges/iter (e, e+4)
                size_t p0 = (size_t)csr_src[e] * row_u4 + slice_u4;
                size_t p1 = (size_t)csr_src[e + 4] * row_u4 + slice_u4;
                uint4 a0 = h4[p0 + lane8], a1 = h4[p0 + lane8 + 8];
                uint4 c0 = h4[p1 + lane8], c1 = h4[p1 + lane8 + 8];
                ACC_ROW(a0, a1)
                ACC_ROW(c0, c1)
            }
            if (e < e1) {
                size_t p0 = (size_t)csr_src[e] * row_u4 + slice_u4;
                uint4 a0 = h4[p0 + lane8], a1 = h4[p0 + lane8 + 8];
                ACC_ROW(a0, a1)
            }
#undef ACC_ROW
        }
        // combine across 4 subs (within a node's 32-lane group)
        sa0 += __shfl_xor(sa0, 8);  sa1 += __shfl_xor(sa1, 8);
        sa2 += __shfl_xor(sa2, 8);  sa3 += __shfl_xor(sa3, 8);
        sa4 += __shfl_xor(sa4, 8);  sa5 += __shfl_xor(sa5, 8);
        sa6 += __shfl_xor(sa6, 8);  sa7 += __shfl_xor(sa7, 8);
        sb0 += __shfl_xor(sb0, 8);  sb1 += __shfl_xor(sb1, 8);
        sb2 += __shfl_xor(sb2, 8);  sb3 += __shfl_xor(sb3, 8);
        sb4 += __shfl_xor(sb4, 8);  sb5 += __shfl_xor(sb5, 8);
        sb6 += __shfl_xor(sb6, 8);  sb7 += __shfl_xor(sb7, 8);
        sa0 += __shfl_xor(sa0, 16); sa1 += __shfl_xor(sa1, 16);
        sa2 += __shfl_xor(sa2, 16); sa3 += __shfl_xor(sa3, 16);
        sa4 += __shfl_xor(sa4, 16); sa5 += __shfl_xor(sa5, 16);
        sa6 += __shfl_xor(sa6, 16); sa7 += __shfl_xor(sa7, 16);
        sb0 += __shfl_xor(sb0, 16); sb1 += __shfl_xor(sb1, 16);
        sb2 += __shfl_xor(sb2, 16); sb3 += __shfl_xor(sb3, 16);
        sb4 += __shfl_xor(sb4, 16); sb5 += __shfl_xor(sb5, 16);
        sb6 += __shfl_xor(sb6, 16); sb7 += __shfl_xor(sb7, 16);
        if (sub < 2) {
            uint4 o;
            if (sub == 0) {
                o.x = f2bf(sa0) | ((unsigned)f2bf(sa1) << 16);
                o.y = f2bf(sa2) | ((unsigned)f2bf(sa3) << 16);
                o.z = f2bf(sa4) | ((unsigned)f2bf(sa5) << 16);
                o.w = f2bf(sa6) | ((unsigned)f2bf(sa7) << 16);
            } else {
                o.x = f2bf(sb0) | ((unsigned)f2bf(sb1) << 16);
                o.y = f2bf(sb2) | ((unsigned)f2bf(sb3) << 16);
                o.z = f2bf(sb4) | ((unsigned)f2bf(sb5) << 16);
                o.w = f2bf(sb6) | ((unsigned)f2bf(sb7) << 16);
            }
            int chunk = lane8 + sub * 8;
            *(uint4*)(zt + nl * 256 + ((chunk * 16) ^ ((nl & 7) << 4))) = o;
        }
    }
    __syncthreads();

    int wave = t >> 6, lane = t & 63, l15 = lane & 15, l4 = lane >> 4;
    int colbase = wave * 16;

    f32x4 acc = (f32x4){0.f, 0.f, 0.f, 0.f};

    // ---- GEMM1: A from zt, wave's 16 cols ----
#pragma unroll
    for (int kk = 0; kk < 4; kk++) {
        int k0 = kk * 32 + l4 * 8;
        bf16x8 a0 = *(const bf16x8*)(zt + l15 * 256 + ((k0 * 2) ^ ((l15 & 7) << 4)));
        bf16x8 b = *(const bf16x8*)&Wt1[(size_t)(colbase + l15) * HID + k0];
        acc = __builtin_amdgcn_mfma_f32_16x16x32_bf16(a0, b, acc, 0, 0, 0);
    }

    // ---- epilogue1: relu(acc+b1) -> tt ----
    {
        int col = colbase + l15;
        float bc = b1[col];
#pragma unroll
        for (int j = 0; j < 4; j++) {
            int r = l4 * 4 + j;                     // rows 0..15
            float v = fmaxf(acc[j] + bc, 0.f);
            *(unsigned short*)(tt + r * 256 + ((col * 2) ^ ((r & 7) << 4))) = f2bf(v);
        }
    }
    __syncthreads();

    // ---- GEMM2: A from full tt (K=128), wave's 16 output cols ----
    acc = (f32x4){0.f, 0.f, 0.f, 0.f};
#pragma unroll
    for (int kk = 0; kk < 4; kk++) {
        int k0 = kk * 32 + l4 * 8;
        bf16x8 a0 = *(const bf16x8*)(tt + l15 * 256 + ((k0 * 2) ^ ((l15 & 7) << 4)));
        bf16x8 b = *(const bf16x8*)&Wt2[(size_t)(colbase + l15) * HID + k0];
        acc = __builtin_amdgcn_mfma_f32_16x16x32_bf16(a0, b, acc, 0, 0, 0);
    }

    // ---- epilogue2: +b2 [,+xres bf16], emb slice = relu ----
    {
        int col = colbase + l15;
        float bc = b2[col];
#pragma unroll
        for (int j = 0; j < 4; j++) {
            int r = l4 * 4 + j;
            int rg = rowbase + r;
            if (rg < N) {
                float v = acc[j] + bc;
                if (ODD) {
                    v += bf2f(xres[(size_t)rg * HID + col]);
                    xres[(size_t)rg * HID + col] = f2bf(v);
                }
                h_out[(size_t)rg * out_stride + col] = f2bf(fmaxf(v, 0.f));
            }
        }
    }
}

// ---------------- pre linear (MFMA, global in, writes emb slice 0 + xres bf16) ----------------
__global__ __launch_bounds__(256) void linear_pre(const unsigned short* __restrict__ in,
                                                  const unsigned short* __restrict__ Wt,
                                                  const float* __restrict__ bias,
                                                  unsigned short* __restrict__ out,
                                                  int out_stride,
                                                  unsigned short* __restrict__ pre_out, int M) {
    int tid = threadIdx.x;
    int wave = tid >> 6, lane = tid & 63;
    int l15 = lane & 15, l4 = lane >> 4;
    int rowbase = blockIdx.x * 64 + wave * 16;
    f32x4 acc[8];
#pragma unroll
    for (int ct = 0; ct < 8; ct++) acc[ct] = (f32x4){0.f, 0.f, 0.f, 0.f};
    int r0 = min(rowbase + l15, M - 1);
#pragma unroll
    for (int kk = 0; kk < 4; kk++) {
        int k0 = kk * 32 + l4 * 8;
        bf16x8 a0 = *(const bf16x8*)&in[(size_t)r0 * HID + k0];
#pragma unroll
        for (int ct = 0; ct < 8; ct++) {
            bf16x8 b = *(const bf16x8*)&Wt[(size_t)(ct * 16 + l15) * HID + k0];
            acc[ct] = __builtin_amdgcn_mfma_f32_16x16x32_bf16(a0, b, acc[ct], 0, 0, 0);
        }
    }
#pragma unroll
    for (int ct = 0; ct < 8; ct++) {
        int col = ct * 16 + l15;
        float bc = bias[col];
#pragma unroll
        for (int j = 0; j < 4; j++) {
            int r = rowbase + l4 * 4 + j;
            if (r < M) {
                float v = acc[ct][j] + bc;
                unsigned short bv = f2bf(v);
                pre_out[(size_t)r * HID + col] = bv;          // xres bf16
                out[(size_t)r * out_stride + col] = bv;       // emb slice 0 (no relu)
            }
        }
    }
}

// ---------------- pooling over full emb, 2-level deterministic ----------------
__global__ __launch_bounds__(128) void pool_all(const unsigned short* __restrict__ emb,
                                                const int* __restrict__ gstart,
                                                float* __restrict__ part, int EMB) {
    int g = blockIdx.x >> 3, sub = blockIdx.x & 7;
    int t = threadIdx.x;
    if (t >= 112) return;
    const uint4* e4 = (const uint4*)emb;     // row stride EMB/8 = 112 uint4
    int row_u4 = EMB / 8;
    int n0 = gstart[g], n1 = gstart[g + 1];
    float s[8] = {0.f, 0.f, 0.f, 0.f, 0.f, 0.f, 0.f, 0.f};
    for (int n = n0 + sub; n < n1; n += 8) {
        uint4 v = e4[(size_t)n * row_u4 + t];
        s[0] += bf2f(v.x & 0xffff); s[1] += bf2f(v.x >> 16);
        s[2] += bf2f(v.y & 0xffff); s[3] += bf2f(v.y >> 16);
        s[4] += bf2f(v.z & 0xffff); s[5] += bf2f(v.z >> 16);
        s[6] += bf2f(v.w & 0xffff); s[7] += bf2f(v.w >> 16);
    }
    float4* p4 = (float4*)&part[(size_t)blockIdx.x * EMB + t * 8];
    p4[0] = (float4){s[0], s[1], s[2], s[3]};
    p4[1] = (float4){s[4], s[5], s[6], s[7]};
}

__global__ __launch_bounds__(128) void pool_fin(const float* __restrict__ part,
                                                unsigned short* __restrict__ pooled,
                                                int EMB) {
    int idx = blockIdx.x * 128 + threadIdx.x;   // over G*EMB
    int g = idx / EMB, c = idx - g * EMB;
    float s = 0.f;
#pragma unroll
    for (int sub = 0; sub < 8; sub++)
        s += part[(size_t)(g * 8 + sub) * EMB + c];
    pooled[idx] = f2bf(s);
}

// ---------------- post MLP via MFMA ----------------
__global__ __launch_bounds__(256) void post_mfma(const unsigned short* __restrict__ pooled,
                                                 const unsigned short* __restrict__ w1t,
                                                 const float* __restrict__ b1,
                                                 const unsigned short* __restrict__ w2t,
                                                 const float* __restrict__ b2,
                                                 float* __restrict__ out, int EMB) {
    __shared__ __align__(16) char lds[128 * 256];
    int t = threadIdx.x;
    int wave = t >> 6, lane = t & 63, l15 = lane & 15, l4 = lane >> 4;
    int wrow = wave * 32;
    f32x4 acc[2][8];
#pragma unroll
    for (int rt = 0; rt < 2; rt++)
#pragma unroll
        for (int ct = 0; ct < 8; ct++) acc[rt][ct] = (f32x4){0.f, 0.f, 0.f, 0.f};
    int r0 = wrow + l15, r1 = r0 + 16;
#pragma unroll 4
    for (int kk = 0; kk < EMB / 32; kk++) {
        int k0 = kk * 32 + l4 * 8;
        bf16x8 a0 = *(const bf16x8*)&pooled[(size_t)r0 * EMB + k0];
        bf16x8 a1 = *(const bf16x8*)&pooled[(size_t)r1 * EMB + k0];
#pragma unroll
        for (int ct = 0; ct < 8; ct++) {
            bf16x8 b = *(const bf16x8*)&w1t[(size_t)(ct * 16 + l15) * EMB + k0];
            acc[0][ct] = __builtin_amdgcn_mfma_f32_16x16x32_bf16(a0, b, acc[0][ct], 0, 0, 0);
            acc[1][ct] = __builtin_amdgcn_mfma_f32_16x16x32_bf16(a1, b, acc[1][ct], 0, 0, 0);
        }
    }
#pragma unroll
    for (int ct = 0; ct < 8; ct++) {
        int col = ct * 16 + l15;
        float bc = b1[col];
#pragma unroll
        for (int rt = 0; rt < 2; rt++)
#pragma unroll
            for (int j = 0; j < 4; j++) {
                int r = wrow + rt * 16 + l4 * 4 + j;
                float v = fmaxf(acc[rt][ct][j] + bc, 0.f);
                *(unsigned short*)(lds + r * 256 + ((col * 2) ^ ((r & 7) << 4))) = f2bf(v);
            }
    }
    __syncthreads();
#pragma unroll
    for (int rt = 0; rt < 2; rt++)
#pragma unroll
        for (int ct = 0; ct < 8; ct++) acc[rt][ct] = (f32x4){0.f, 0.f, 0.f, 0.f};
#pragma unroll
    for (int kk = 0; kk < 4; kk++) {
        int k0 = kk * 32 + l4 * 8;
        bf16x8 a0 = *(const bf16x8*)(lds + r0 * 256 + ((k0 * 2) ^ ((r0 & 7) << 4)));
        bf16x8 a1 = *(const bf16x8*)(lds + r1 * 256 + ((k0 * 2) ^ ((r1 & 7) << 4)));
#pragma unroll
        for (int ct = 0; ct < 8; ct++) {
            bf16x8 b = *(const bf16x8*)&w2t[(size_t)(ct * 16 + l15) * HID + k0];
            acc[0][ct] = __builtin_amdgcn_mfma_f32_16x16x32_bf16(a0, b, acc[0][ct], 0, 0, 0);
            acc[1][ct] = __builtin_amdgcn_mfma_f32_16x16x32_bf16(a1, b, acc[1][ct], 0, 0, 0);
        }
    }
#pragma unroll
    for (int ct = 0; ct < 8; ct++) {
        int col = ct * 16 + l15;
        float bc = b2[col];
#pragma unroll
        for (int rt = 0; rt < 2; rt++)
#pragma unroll
            for (int j = 0; j < 4; j++) {
                int r = wrow + rt * 16 + l4 * 4 + j;
                out[(size_t)r * HID + col] = acc[rt][ct][j] + bc;
            }
    }
}

// ---------------- launch ----------------

extern "C" void kernel_launch(void* const* d_in, const int* in_sizes, int n_in,
                              void* d_out, int out_size, void* d_ws, size_t ws_size,
                              hipStream_t stream) {
    const float* x       = (const float*)d_in[0];
    const int* edge_index= (const int*)d_in[1];
    const int* batch     = (const int*)d_in[2];
    const float* pre_w   = (const float*)d_in[3];
    const float* pre_b   = (const float*)d_in[4];
    const float* conv_w1 = (const float*)d_in[5];
    const float* conv_b1 = (const float*)d_in[6];
    const float* conv_w2 = (const float*)d_in[7];
    const float* conv_b2 = (const float*)d_in[8];
    const float* post_w1 = (const float*)d_in[9];
    const float* post_b1 = (const float*)d_in[10];
    const float* post_w2 = (const float*)d_in[11];
    const float* post_b2 = (const float*)d_in[12];
    float* outp = (float*)d_out;

    int N = in_sizes[0] / HID;
    int E = in_sizes[1] / 2;
    int L = in_sizes[5] / (HID * HID);
    int G = out_size / HID;
    int EMB = (L + 1) * HID;

    const int* src = edge_index;
    const int* dst = edge_index + E;

    char* w = (char*)d_ws;
    auto alloc = [&](size_t bytes) -> char* {
        char* p = w;
        w += (bytes + 255) & ~(size_t)255;
        return p;
    };
    unsigned short* emb   = (unsigned short*)alloc((size_t)N * EMB * 2);     // all layer embeddings
    unsigned short* x_bf  = (unsigned short*)alloc((size_t)N * HID * 2);
    unsigned short* xres  = (unsigned short*)alloc((size_t)N * HID * 2);     // bf16 residual
    float* part   = (float*)alloc((size_t)G * 8 * EMB * 4);
    unsigned short* pooled = (unsigned short*)alloc((size_t)G * EMB * 2);
    unsigned short* Wt_pre = (unsigned short*)alloc((size_t)HID * HID * 2);
    unsigned short* Wt_c1  = (unsigned short*)alloc((size_t)L * HID * HID * 2);
    unsigned short* Wt_c2  = (unsigned short*)alloc((size_t)L * HID * HID * 2);
    unsigned short* w1t    = (unsigned short*)alloc((size_t)EMB * HID * 2);
    unsigned short* w2t    = (unsigned short*)alloc((size_t)HID * HID * 2);
    int* deg      = (int*)alloc((size_t)(N + 1) * 4);
    int* row_ptr  = (int*)alloc((size_t)(N + 1) * 4);
    int* pos      = (int*)alloc((size_t)(N + 1) * 4);
    int* bsum     = (int*)alloc((size_t)1024 * 4);
    int* bstart   = (int*)alloc((size_t)1024 * 4);
    int* csr_src  = (int*)alloc((size_t)E * 4);
    int* gstart   = (int*)alloc((size_t)(G + 1) * 4);
    (void)ws_size; (void)n_in;

    int eb = (E + 255) / 256;
    int nb = (N + 255) / 256;

    // CSR by dst
    zero_i32<<<nb, 256, 0, stream>>>(deg, N);
    count_deg<<<eb, 256, 0, stream>>>(dst, deg, E);
    block_sums<<<nb, 256, 0, stream>>>(deg, bsum, N);
    scan_bsums<<<1, 1024, 0, stream>>>(bsum, bstart, nb);
    scan_within<<<nb, 256, 0, stream>>>(deg, bstart, row_ptr, pos, N);
    fill_csr<<<eb, 256, 0, stream>>>(src, dst, pos, csr_src, E);
    graph_starts<<<1, 256, 0, stream>>>(batch, gstart, N, G);

    // conversions / transposes
    f32_to_bf16_vec<<<(N * HID / 8 + 255) / 256, 256, 0, stream>>>(x, x_bf, N * HID / 8);
    transpose_kc<<<(HID * HID + 255) / 256, 256, 0, stream>>>(pre_w, Wt_pre, HID, HID, HID * HID);
    transpose_kc<<<(L * HID * HID + 255) / 256, 256, 0, stream>>>(conv_w1, Wt_c1, HID, HID, L * HID * HID);
    transpose_kc<<<(L * HID * HID + 255) / 256, 256, 0, stream>>>(conv_w2, Wt_c2, HID, HID, L * HID * HID);
    transpose_kc<<<(EMB * HID + 255) / 256, 256, 0, stream>>>(post_w1, w1t, EMB, HID, EMB * HID);
    transpose_kc<<<(HID * HID + 255) / 256, 256, 0, stream>>>(post_w2, w2t, HID, HID, HID * HID);

    int gb64 = (N + 63) / 64;
    int gb16 = (N + 15) / 16;

    // pre linear: emb slice0 = x@pre_w + pre_b (no relu) ; xres = same (bf16)
    linear_pre<<<gb64, 256, 0, stream>>>(x_bf, Wt_pre, pre_b, emb, EMB, xres, N);

    for (int i = 0; i < L; i++) {
        unsigned short* slice_out = emb + (size_t)(i + 1) * HID;
        if (i & 1) {
            fused_layer<true><<<gb16, 512, 0, stream>>>(
                emb, i * 16, EMB / 8, row_ptr, csr_src,
                Wt_c1 + (size_t)i * HID * HID, conv_b1 + i * HID,
                Wt_c2 + (size_t)i * HID * HID, conv_b2 + i * HID,
                xres, slice_out, EMB, N);
        } else {
            fused_layer<false><<<gb16, 512, 0, stream>>>(
                emb, i * 16, EMB / 8, row_ptr, csr_src,
                Wt_c1 + (size_t)i * HID * HID, conv_b1 + i * HID,
                Wt_c2 + (size_t)i * HID * HID, conv_b2 + i * HID,
                xres, slice_out, EMB, N);
        }
    }

    pool_all<<<G * 8, 128, 0, stream>>>(emb, gstart, part, EMB);
    pool_fin<<<(G * EMB) / 128, 128, 0, stream>>>(part, pooled, EMB);
    post_mfma<<<1, 256, 0, stream>>>(pooled, w1t, post_b1, w2t, post_b2, outp, EMB);
}

// Round 12
// 518.709 us; speedup vs baseline: 1.1195x; 1.0315x over previous
//
#include <hip/hip_runtime.h>
#include <hip/hip_bf16.h>

#define HID 128

using bf16x8 = __attribute__((ext_vector_type(8))) short;
using f32x4  = __attribute__((ext_vector_type(4))) float;

__device__ inline float bf2f(unsigned int u16) {
    union { float f; unsigned int i; } v; v.i = u16 << 16; return v.f;
}
__device__ inline unsigned short f2bf(float f) {
    __hip_bfloat16 h = __float2bfloat16(f);        // RNE
    return *reinterpret_cast<unsigned short*>(&h);
}

// ---------------- CSR build ----------------

__global__ void zero_i32(int* __restrict__ p, int n) {
    int i = blockIdx.x * blockDim.x + threadIdx.x;
    if (i < n) p[i] = 0;
}

__global__ void count_deg(const int* __restrict__ dst, int* __restrict__ deg, int E) {
    int e = blockIdx.x * blockDim.x + threadIdx.x;
    if (e < E) atomicAdd(&deg[dst[e]], 1);
}

__global__ __launch_bounds__(256) void block_sums(const int* __restrict__ deg,
                                                  int* __restrict__ bsum, int n) {
    __shared__ int red[256];
    int t = threadIdx.x;
    int i = blockIdx.x * 256 + t;
    red[t] = (i < n) ? deg[i] : 0;
    __syncthreads();
    for (int off = 128; off > 0; off >>= 1) {
        if (t < off) red[t] += red[t + off];
        __syncthreads();
    }
    if (t == 0) bsum[blockIdx.x] = red[0];
}

__global__ __launch_bounds__(1024) void scan_bsums(const int* __restrict__ bsum,
                                                   int* __restrict__ bstart, int nb) {
    __shared__ int s[1024];
    int t = threadIdx.x;
    s[t] = (t < nb) ? bsum[t] : 0;
    __syncthreads();
    for (int off = 1; off < 1024; off <<= 1) {
        int v = (t >= off) ? s[t - off] : 0;
        __syncthreads();
        s[t] += v;
        __syncthreads();
    }
    if (t < nb) bstart[t] = (t == 0) ? 0 : s[t - 1];
}

__global__ __launch_bounds__(256) void scan_within(const int* __restrict__ deg,
                                                   const int* __restrict__ bstart,
                                                   int* __restrict__ row_ptr,
                                                   int* __restrict__ pos, int n) {
    __shared__ int s[256];
    int b = blockIdx.x, t = threadIdx.x;
    int i = b * 256 + t;
    int v = (i < n) ? deg[i] : 0;
    s[t] = v;
    __syncthreads();
    for (int off = 1; off < 256; off <<= 1) {
        int u = (t >= off) ? s[t - off] : 0;
        __syncthreads();
        s[t] += u;
        __syncthreads();
    }
    if (i < n) {
        int excl = bstart[b] + s[t] - v;
        row_ptr[i] = excl;
        pos[i] = excl;
        if (i == n - 1) row_ptr[n] = bstart[b] + s[t];
    }
}

__global__ void fill_csr(const int* __restrict__ src, const int* __restrict__ dst,
                         int* __restrict__ pos, int* __restrict__ csr_src, int E) {
    int e = blockIdx.x * blockDim.x + threadIdx.x;
    if (e < E) {
        int p = atomicAdd(&pos[dst[e]], 1);
        csr_src[p] = src[e];
    }
}

__global__ void graph_starts(const int* __restrict__ batch, int* __restrict__ gstart,
                             int n, int G) {
    int g = blockIdx.x * blockDim.x + threadIdx.x;
    if (g > G) return;
    int lo = 0, hi = n;
    while (lo < hi) { int m = (lo + hi) >> 1; if (batch[m] < g) lo = m + 1; else hi = m; }
    gstart[g] = lo;
}

// ---------------- weight transposes ----------------
// all 128x128 mats in one launch: mat_id 0 = pre_w; 1..L = conv_w1; L+1..2L = conv_w2; 2L+1 = post_w2
__global__ void transpose128_all(const float* __restrict__ pre_w,
                                 const float* __restrict__ conv_w1,
                                 const float* __restrict__ conv_w2,
                                 const float* __restrict__ post_w2,
                                 unsigned short* __restrict__ Wt_pre,
                                 unsigned short* __restrict__ Wt_c1,
                                 unsigned short* __restrict__ Wt_c2,
                                 unsigned short* __restrict__ w2t,
                                 int L, int total) {
    int tid = blockIdx.x * blockDim.x + threadIdx.x;
    if (tid >= total) return;
    int mat = tid >> 14;
    int idx = tid & 16383;
    int c = idx >> 7, k = idx & 127;
    const float* srcm;
    unsigned short* dstm;
    if (mat == 0)            { srcm = pre_w;                                 dstm = Wt_pre; }
    else if (mat <= L)       { srcm = conv_w1 + (size_t)(mat - 1) * 16384;   dstm = Wt_c1 + (size_t)(mat - 1) * 16384; }
    else if (mat <= 2 * L)   { srcm = conv_w2 + (size_t)(mat - 1 - L) * 16384; dstm = Wt_c2 + (size_t)(mat - 1 - L) * 16384; }
    else                     { srcm = post_w2;                               dstm = w2t; }
    dstm[idx] = f2bf(srcm[(size_t)k * HID + c]);
}

// W[k][c] fp32 -> Wt[c][k] bf16 (post_w1, K=EMB)
__global__ void transpose_kc(const float* __restrict__ W, unsigned short* __restrict__ Wt,
                             int K, int C, int total) {
    int tid = blockIdx.x * blockDim.x + threadIdx.x;
    if (tid >= total) return;
    int c = tid / K;
    int k = tid - c * K;
    Wt[tid] = f2bf(W[(size_t)k * C + c]);
}

// ---------------- fused GIN layer (gather + MLP), 4-wave, 2-way edge-split ----------------
// block = 256 thr = 4 waves, 16 node rows.  [R9 best-measured shape: 57 µs, occ 61%]
// Gather: 16 lanes/node = 2 subs x 8 chunk-lanes; sub s walks edges e0+s, e0+s+2,...
//   (2 uint4 chains, unroll 2 -> 4 loads in flight); pair combines via shfl_xor(8).
// GEMM1: wave w computes cols [w*32,w*32+32) from zt; relu -> tt.
// GEMM2: A from tt (K=128); +b2 [,+xres bf16]; emb slice = relu.
template <bool ODD>
__global__ __launch_bounds__(256) void fused_layer(const unsigned short* __restrict__ emb,
                                                   int slice_u4, int row_u4,
                                                   const int* __restrict__ row_ptr,
                                                   const int* __restrict__ csr_src,
                                                   const unsigned short* __restrict__ Wt1,
                                                   const float* __restrict__ b1,
                                                   const unsigned short* __restrict__ Wt2,
                                                   const float* __restrict__ b2,
                                                   unsigned short* __restrict__ xres,
                                                   unsigned short* __restrict__ h_out,
                                                   int out_stride, int N) {
    __shared__ __align__(16) char zt[16 * 256];    // z tile bf16, XOR-swizzled
    __shared__ __align__(16) char tt[16 * 256];    // t tile bf16, XOR-swizzled
    int t = threadIdx.x;
    int rowbase = blockIdx.x * 16;

    // ---- gather (edge-split across sub pairs) ----
    {
        int nl = t >> 4;                 // local node 0..15
        int sub = (t >> 3) & 1;          // edge-parity half
        int lane8 = t & 7;               // chunk lane (chains lane8, lane8+8)
        int node = rowbase + nl;
        const uint4* h4 = (const uint4*)emb;
        float sa0=0,sa1=0,sa2=0,sa3=0,sa4=0,sa5=0,sa6=0,sa7=0;
        float sb0=0,sb1=0,sb2=0,sb3=0,sb4=0,sb5=0,sb6=0,sb7=0;
        if (node < N) {
            if (sub == 0) {
                size_t base = (size_t)node * row_u4 + slice_u4;
                uint4 u0 = h4[base + lane8];
                uint4 u1 = h4[base + lane8 + 8];
                sa0 = bf2f(u0.x & 0xffff); sa1 = bf2f(u0.x >> 16);
                sa2 = bf2f(u0.y & 0xffff); sa3 = bf2f(u0.y >> 16);
                sa4 = bf2f(u0.z & 0xffff); sa5 = bf2f(u0.z >> 16);
                sa6 = bf2f(u0.w & 0xffff); sa7 = bf2f(u0.w >> 16);
                sb0 = bf2f(u1.x & 0xffff); sb1 = bf2f(u1.x >> 16);
                sb2 = bf2f(u1.y & 0xffff); sb3 = bf2f(u1.y >> 16);
                sb4 = bf2f(u1.z & 0xffff); sb5 = bf2f(u1.z >> 16);
                sb6 = bf2f(u1.w & 0xffff); sb7 = bf2f(u1.w >> 16);
            }
            int e0 = row_ptr[node], e1 = row_ptr[node + 1];
            int e = e0 + sub;
            for (; e + 2 < e1; e += 4) {             // this sub's edges, unroll 2
                int i0 = csr_src[e], i1 = csr_src[e + 2];
                size_t p0 = (size_t)i0 * row_u4 + slice_u4;
                size_t p1 = (size_t)i1 * row_u4 + slice_u4;
                uint4 v0 = h4[p0 + lane8];
                uint4 v1 = h4[p0 + lane8 + 8];
                uint4 w0 = h4[p1 + lane8];
                uint4 w1 = h4[p1 + lane8 + 8];
                sa0 += bf2f(v0.x & 0xffff); sa1 += bf2f(v0.x >> 16);
                sa2 += bf2f(v0.y & 0xffff); sa3 += bf2f(v0.y >> 16);
                sa4 += bf2f(v0.z & 0xffff); sa5 += bf2f(v0.z >> 16);
                sa6 += bf2f(v0.w & 0xffff); sa7 += bf2f(v0.w >> 16);
                sb0 += bf2f(v1.x & 0xffff); sb1 += bf2f(v1.x >> 16);
                sb2 += bf2f(v1.y & 0xffff); sb3 += bf2f(v1.y >> 16);
                sb4 += bf2f(v1.z & 0xffff); sb5 += bf2f(v1.z >> 16);
                sb6 += bf2f(v1.w & 0xffff); sb7 += bf2f(v1.w >> 16);
                sa0 += bf2f(w0.x & 0xffff); sa1 += bf2f(w0.x >> 16);
                sa2 += bf2f(w0.y & 0xffff); sa3 += bf2f(w0.y >> 16);
                sa4 += bf2f(w0.z & 0xffff); sa5 += bf2f(w0.z >> 16);
                sa6 += bf2f(w0.w & 0xffff); sa7 += bf2f(w0.w >> 16);
                sb0 += bf2f(w1.x & 0xffff); sb1 += bf2f(w1.x >> 16);
                sb2 += bf2f(w1.y & 0xffff); sb3 += bf2f(w1.y >> 16);
                sb4 += bf2f(w1.z & 0xffff); sb5 += bf2f(w1.z >> 16);
                sb6 += bf2f(w1.w & 0xffff); sb7 += bf2f(w1.w >> 16);
            }
            if (e < e1) {
                size_t p0 = (size_t)csr_src[e] * row_u4 + slice_u4;
                uint4 v0 = h4[p0 + lane8];
                uint4 v1 = h4[p0 + lane8 + 8];
                sa0 += bf2f(v0.x & 0xffff); sa1 += bf2f(v0.x >> 16);
                sa2 += bf2f(v0.y & 0xffff); sa3 += bf2f(v0.y >> 16);
                sa4 += bf2f(v0.z & 0xffff); sa5 += bf2f(v0.z >> 16);
                sa6 += bf2f(v0.w & 0xffff); sa7 += bf2f(v0.w >> 16);
                sb0 += bf2f(v1.x & 0xffff); sb1 += bf2f(v1.x >> 16);
                sb2 += bf2f(v1.y & 0xffff); sb3 += bf2f(v1.y >> 16);
                sb4 += bf2f(v1.z & 0xffff); sb5 += bf2f(v1.z >> 16);
                sb6 += bf2f(v1.w & 0xffff); sb7 += bf2f(v1.w >> 16);
            }
        }
        // pair-combine (t <-> t^8): both subs end with full sums
        sa0 += __shfl_xor(sa0, 8); sa1 += __shfl_xor(sa1, 8);
        sa2 += __shfl_xor(sa2, 8); sa3 += __shfl_xor(sa3, 8);
        sa4 += __shfl_xor(sa4, 8); sa5 += __shfl_xor(sa5, 8);
        sa6 += __shfl_xor(sa6, 8); sa7 += __shfl_xor(sa7, 8);
        sb0 += __shfl_xor(sb0, 8); sb1 += __shfl_xor(sb1, 8);
        sb2 += __shfl_xor(sb2, 8); sb3 += __shfl_xor(sb3, 8);
        sb4 += __shfl_xor(sb4, 8); sb5 += __shfl_xor(sb5, 8);
        sb6 += __shfl_xor(sb6, 8); sb7 += __shfl_xor(sb7, 8);
        // sub0 writes chain lane8 (sa), sub1 writes chain lane8+8 (sb)
        uint4 o;
        if (sub == 0) {
            o.x = f2bf(sa0) | ((unsigned)f2bf(sa1) << 16);
            o.y = f2bf(sa2) | ((unsigned)f2bf(sa3) << 16);
            o.z = f2bf(sa4) | ((unsigned)f2bf(sa5) << 16);
            o.w = f2bf(sa6) | ((unsigned)f2bf(sa7) << 16);
        } else {
            o.x = f2bf(sb0) | ((unsigned)f2bf(sb1) << 16);
            o.y = f2bf(sb2) | ((unsigned)f2bf(sb3) << 16);
            o.z = f2bf(sb4) | ((unsigned)f2bf(sb5) << 16);
            o.w = f2bf(sb6) | ((unsigned)f2bf(sb7) << 16);
        }
        int chunk = lane8 + sub * 8;
        *(uint4*)(zt + nl * 256 + ((chunk * 16) ^ ((nl & 7) << 4))) = o;
    }
    __syncthreads();

    int wave = t >> 6, lane = t & 63, l15 = lane & 15, l4 = lane >> 4;
    int colbase = wave * 32;

    f32x4 acc[2];
#pragma unroll
    for (int ct = 0; ct < 2; ct++) acc[ct] = (f32x4){0.f, 0.f, 0.f, 0.f};

    // ---- GEMM1: A from zt, wave's 32 cols ----
#pragma unroll
    for (int kk = 0; kk < 4; kk++) {
        int k0 = kk * 32 + l4 * 8;
        bf16x8 a0 = *(const bf16x8*)(zt + l15 * 256 + ((k0 * 2) ^ ((l15 & 7) << 4)));
#pragma unroll
        for (int ct = 0; ct < 2; ct++) {
            bf16x8 b = *(const bf16x8*)&Wt1[(size_t)(colbase + ct * 16 + l15) * HID + k0];
            acc[ct] = __builtin_amdgcn_mfma_f32_16x16x32_bf16(a0, b, acc[ct], 0, 0, 0);
        }
    }

    // ---- epilogue1: relu(acc+b1) -> tt ----
#pragma unroll
    for (int ct = 0; ct < 2; ct++) {
        int col = colbase + ct * 16 + l15;
        float bc = b1[col];
#pragma unroll
        for (int j = 0; j < 4; j++) {
            int r = l4 * 4 + j;                     // rows 0..15
            float v = fmaxf(acc[ct][j] + bc, 0.f);
            *(unsigned short*)(tt + r * 256 + ((col * 2) ^ ((r & 7) << 4))) = f2bf(v);
        }
    }
    __syncthreads();

    // ---- GEMM2: A from full tt (K=128), wave's 32 output cols ----
#pragma unroll
    for (int ct = 0; ct < 2; ct++) acc[ct] = (f32x4){0.f, 0.f, 0.f, 0.f};
#pragma unroll
    for (int kk = 0; kk < 4; kk++) {
        int k0 = kk * 32 + l4 * 8;
        bf16x8 a0 = *(const bf16x8*)(tt + l15 * 256 + ((k0 * 2) ^ ((l15 & 7) << 4)));
#pragma unroll
        for (int ct = 0; ct < 2; ct++) {
            bf16x8 b = *(const bf16x8*)&Wt2[(size_t)(colbase + ct * 16 + l15) * HID + k0];
            acc[ct] = __builtin_amdgcn_mfma_f32_16x16x32_bf16(a0, b, acc[ct], 0, 0, 0);
        }
    }

    // ---- epilogue2: +b2 [,+xres bf16], emb slice = relu ----
#pragma unroll
    for (int ct = 0; ct < 2; ct++) {
        int col = colbase + ct * 16 + l15;
        float bc = b2[col];
#pragma unroll
        for (int j = 0; j < 4; j++) {
            int r = l4 * 4 + j;
            int rg = rowbase + r;
            if (rg < N) {
                float v = acc[ct][j] + bc;
                if (ODD) {
                    v += bf2f(xres[(size_t)rg * HID + col]);
                    xres[(size_t)rg * HID + col] = f2bf(v);
                }
                h_out[(size_t)rg * out_stride + col] = f2bf(fmaxf(v, 0.f));
            }
        }
    }
}

// ---------------- pre linear (MFMA, fp32 x in, writes emb slice 0 + xres bf16) ----------------
__global__ __launch_bounds__(256) void linear_pre(const float* __restrict__ x,
                                                  const unsigned short* __restrict__ Wt,
                                                  const float* __restrict__ bias,
                                                  unsigned short* __restrict__ out,
                                                  int out_stride,
                                                  unsigned short* __restrict__ pre_out, int M) {
    int tid = threadIdx.x;
    int wave = tid >> 6, lane = tid & 63;
    int l15 = lane & 15, l4 = lane >> 4;
    int rowbase = blockIdx.x * 64 + wave * 16;
    f32x4 acc[8];
#pragma unroll
    for (int ct = 0; ct < 8; ct++) acc[ct] = (f32x4){0.f, 0.f, 0.f, 0.f};
    int r0 = min(rowbase + l15, M - 1);
    const float4* xf = (const float4*)x;
#pragma unroll
    for (int kk = 0; kk < 4; kk++) {
        int k0 = kk * 32 + l4 * 8;
        float4 m0 = xf[(size_t)r0 * 32 + k0 / 4];
        float4 m1 = xf[(size_t)r0 * 32 + k0 / 4 + 1];
        bf16x8 a0;
        unsigned short* ap = (unsigned short*)&a0;
        ap[0] = f2bf(m0.x); ap[1] = f2bf(m0.y); ap[2] = f2bf(m0.z); ap[3] = f2bf(m0.w);
        ap[4] = f2bf(m1.x); ap[5] = f2bf(m1.y); ap[6] = f2bf(m1.z); ap[7] = f2bf(m1.w);
#pragma unroll
        for (int ct = 0; ct < 8; ct++) {
            bf16x8 b = *(const bf16x8*)&Wt[(size_t)(ct * 16 + l15) * HID + k0];
            acc[ct] = __builtin_amdgcn_mfma_f32_16x16x32_bf16(a0, b, acc[ct], 0, 0, 0);
        }
    }
#pragma unroll
    for (int ct = 0; ct < 8; ct++) {
        int col = ct * 16 + l15;
        float bc = bias[col];
#pragma unroll
        for (int j = 0; j < 4; j++) {
            int r = rowbase + l4 * 4 + j;
            if (r < M) {
                float v = acc[ct][j] + bc;
                unsigned short bv = f2bf(v);
                pre_out[(size_t)r * HID + col] = bv;          // xres bf16
                out[(size_t)r * out_stride + col] = bv;       // emb slice 0 (no relu)
            }
        }
    }
}

// ---------------- pooling over full emb, 2-level deterministic ----------------
__global__ __launch_bounds__(128) void pool_all(const unsigned short* __restrict__ emb,
                                                const int* __restrict__ gstart,
                                                float* __restrict__ part, int EMB) {
    int g = blockIdx.x >> 3, sub = blockIdx.x & 7;
    int t = threadIdx.x;
    if (t >= 112) return;
    const uint4* e4 = (const uint4*)emb;     // row stride EMB/8 = 112 uint4
    int row_u4 = EMB / 8;
    int n0 = gstart[g], n1 = gstart[g + 1];
    float s[8] = {0.f, 0.f, 0.f, 0.f, 0.f, 0.f, 0.f, 0.f};
    for (int n = n0 + sub; n < n1; n += 8) {
        uint4 v = e4[(size_t)n * row_u4 + t];
        s[0] += bf2f(v.x & 0xffff); s[1] += bf2f(v.x >> 16);
        s[2] += bf2f(v.y & 0xffff); s[3] += bf2f(v.y >> 16);
        s[4] += bf2f(v.z & 0xffff); s[5] += bf2f(v.z >> 16);
        s[6] += bf2f(v.w & 0xffff); s[7] += bf2f(v.w >> 16);
    }
    float4* p4 = (float4*)&part[(size_t)blockIdx.x * EMB + t * 8];
    p4[0] = (float4){s[0], s[1], s[2], s[3]};
    p4[1] = (float4){s[4], s[5], s[6], s[7]};
}

__global__ __launch_bounds__(128) void pool_fin(const float* __restrict__ part,
                                                unsigned short* __restrict__ pooled,
                                                int EMB) {
    int idx = blockIdx.x * 128 + threadIdx.x;   // over G*EMB
    int g = idx / EMB, c = idx - g * EMB;
    float s = 0.f;
#pragma unroll
    for (int sub = 0; sub < 8; sub++)
        s += part[(size_t)(g * 8 + sub) * EMB + c];
    pooled[idx] = f2bf(s);
}

// ---------------- post MLP via MFMA ----------------
__global__ __launch_bounds__(256) void post_mfma(const unsigned short* __restrict__ pooled,
                                                 const unsigned short* __restrict__ w1t,
                                                 const float* __restrict__ b1,
                                                 const unsigned short* __restrict__ w2t,
                                                 const float* __restrict__ b2,
                                                 float* __restrict__ out, int EMB) {
    __shared__ __align__(16) char lds[128 * 256];
    int t = threadIdx.x;
    int wave = t >> 6, lane = t & 63, l15 = lane & 15, l4 = lane >> 4;
    int wrow = wave * 32;
    f32x4 acc[2][8];
#pragma unroll
    for (int rt = 0; rt < 2; rt++)
#pragma unroll
        for (int ct = 0; ct < 8; ct++) acc[rt][ct] = (f32x4){0.f, 0.f, 0.f, 0.f};
    int r0 = wrow + l15, r1 = r0 + 16;
#pragma unroll 4
    for (int kk = 0; kk < EMB / 32; kk++) {
        int k0 = kk * 32 + l4 * 8;
        bf16x8 a0 = *(const bf16x8*)&pooled[(size_t)r0 * EMB + k0];
        bf16x8 a1 = *(const bf16x8*)&pooled[(size_t)r1 * EMB + k0];
#pragma unroll
        for (int ct = 0; ct < 8; ct++) {
            bf16x8 b = *(const bf16x8*)&w1t[(size_t)(ct * 16 + l15) * EMB + k0];
            acc[0][ct] = __builtin_amdgcn_mfma_f32_16x16x32_bf16(a0, b, acc[0][ct], 0, 0, 0);
            acc[1][ct] = __builtin_amdgcn_mfma_f32_16x16x32_bf16(a1, b, acc[1][ct], 0, 0, 0);
        }
    }
#pragma unroll
    for (int ct = 0; ct < 8; ct++) {
        int col = ct * 16 + l15;
        float bc = b1[col];
#pragma unroll
        for (int rt = 0; rt < 2; rt++)
#pragma unroll
            for (int j = 0; j < 4; j++) {
                int r = wrow + rt * 16 + l4 * 4 + j;
                float v = fmaxf(acc[rt][ct][j] + bc, 0.f);
                *(unsigned short*)(lds + r * 256 + ((col * 2) ^ ((r & 7) << 4))) = f2bf(v);
            }
    }
    __syncthreads();
#pragma unroll
    for (int rt = 0; rt < 2; rt++)
#pragma unroll
        for (int ct = 0; ct < 8; ct++) acc[rt][ct] = (f32x4){0.f, 0.f, 0.f, 0.f};
#pragma unroll
    for (int kk = 0; kk < 4; kk++) {
        int k0 = kk * 32 + l4 * 8;
        bf16x8 a0 = *(const bf16x8*)(lds + r0 * 256 + ((k0 * 2) ^ ((r0 & 7) << 4)));
        bf16x8 a1 = *(const bf16x8*)(lds + r1 * 256 + ((k0 * 2) ^ ((r1 & 7) << 4)));
#pragma unroll
        for (int ct = 0; ct < 8; ct++) {
            bf16x8 b = *(const bf16x8*)&w2t[(size_t)(ct * 16 + l15) * HID + k0];
            acc[0][ct] = __builtin_amdgcn_mfma_f32_16x16x32_bf16(a0, b, acc[0][ct], 0, 0, 0);
            acc[1][ct] = __builtin_amdgcn_mfma_f32_16x16x32_bf16(a1, b, acc[1][ct], 0, 0, 0);
        }
    }
#pragma unroll
    for (int ct = 0; ct < 8; ct++) {
        int col = ct * 16 + l15;
        float bc = b2[col];
#pragma unroll
        for (int rt = 0; rt < 2; rt++)
#pragma unroll
            for (int j = 0; j < 4; j++) {
                int r = wrow + rt * 16 + l4 * 4 + j;
                out[(size_t)r * HID + col] = acc[rt][ct][j] + bc;
            }
    }
}

// ---------------- launch ----------------

extern "C" void kernel_launch(void* const* d_in, const int* in_sizes, int n_in,
                              void* d_out, int out_size, void* d_ws, size_t ws_size,
                              hipStream_t stream) {
    const float* x       = (const float*)d_in[0];
    const int* edge_index= (const int*)d_in[1];
    const int* batch     = (const int*)d_in[2];
    const float* pre_w   = (const float*)d_in[3];
    const float* pre_b   = (const float*)d_in[4];
    const float* conv_w1 = (const float*)d_in[5];
    const float* conv_b1 = (const float*)d_in[6];
    const float* conv_w2 = (const float*)d_in[7];
    const float* conv_b2 = (const float*)d_in[8];
    const float* post_w1 = (const float*)d_in[9];
    const float* post_b1 = (const float*)d_in[10];
    const float* post_w2 = (const float*)d_in[11];
    const float* post_b2 = (const float*)d_in[12];
    float* outp = (float*)d_out;

    int N = in_sizes[0] / HID;
    int E = in_sizes[1] / 2;
    int L = in_sizes[5] / (HID * HID);
    int G = out_size / HID;
    int EMB = (L + 1) * HID;

    const int* src = edge_index;
    const int* dst = edge_index + E;

    char* w = (char*)d_ws;
    auto alloc = [&](size_t bytes) -> char* {
        char* p = w;
        w += (bytes + 255) & ~(size_t)255;
        return p;
    };
    unsigned short* emb   = (unsigned short*)alloc((size_t)N * EMB * 2);     // all layer embeddings
    unsigned short* xres  = (unsigned short*)alloc((size_t)N * HID * 2);     // bf16 residual
    float* part   = (float*)alloc((size_t)G * 8 * EMB * 4);
    unsigned short* pooled = (unsigned short*)alloc((size_t)G * EMB * 2);
    unsigned short* Wt_pre = (unsigned short*)alloc((size_t)HID * HID * 2);
    unsigned short* Wt_c1  = (unsigned short*)alloc((size_t)L * HID * HID * 2);
    unsigned short* Wt_c2  = (unsigned short*)alloc((size_t)L * HID * HID * 2);
    unsigned short* w1t    = (unsigned short*)alloc((size_t)EMB * HID * 2);
    unsigned short* w2t    = (unsigned short*)alloc((size_t)HID * HID * 2);
    int* deg      = (int*)alloc((size_t)(N + 1) * 4);
    int* row_ptr  = (int*)alloc((size_t)(N + 1) * 4);
    int* pos      = (int*)alloc((size_t)(N + 1) * 4);
    int* bsum     = (int*)alloc((size_t)1024 * 4);
    int* bstart   = (int*)alloc((size_t)1024 * 4);
    int* csr_src  = (int*)alloc((size_t)E * 4);
    int* gstart   = (int*)alloc((size_t)(G + 1) * 4);
    (void)ws_size; (void)n_in;

    int eb = (E + 255) / 256;
    int nb = (N + 255) / 256;

    // CSR by dst
    zero_i32<<<nb, 256, 0, stream>>>(deg, N);
    count_deg<<<eb, 256, 0, stream>>>(dst, deg, E);
    block_sums<<<nb, 256, 0, stream>>>(deg, bsum, N);
    scan_bsums<<<1, 1024, 0, stream>>>(bsum, bstart, nb);
    scan_within<<<nb, 256, 0, stream>>>(deg, bstart, row_ptr, pos, N);
    fill_csr<<<eb, 256, 0, stream>>>(src, dst, pos, csr_src, E);
    graph_starts<<<1, 256, 0, stream>>>(batch, gstart, N, G);

    // weight transposes: all 128x128 mats in one launch + post_w1 separately
    int t128 = (2 * L + 2) * HID * HID;
    transpose128_all<<<(t128 + 255) / 256, 256, 0, stream>>>(
        pre_w, conv_w1, conv_w2, post_w2, Wt_pre, Wt_c1, Wt_c2, w2t, L, t128);
    transpose_kc<<<(EMB * HID + 255) / 256, 256, 0, stream>>>(post_w1, w1t, EMB, HID, EMB * HID);

    int gb64 = (N + 63) / 64;
    int gb16 = (N + 15) / 16;

    // pre linear: emb slice0 = x@pre_w + pre_b (no relu) ; xres = same (bf16)
    linear_pre<<<gb64, 256, 0, stream>>>(x, Wt_pre, pre_b, emb, EMB, xres, N);

    for (int i = 0; i < L; i++) {
        unsigned short* slice_out = emb + (size_t)(i + 1) * HID;
        if (i & 1) {
            fused_layer<true><<<gb16, 256, 0, stream>>>(
                emb, i * 16, EMB / 8, row_ptr, csr_src,
                Wt_c1 + (size_t)i * HID * HID, conv_b1 + i * HID,
                Wt_c2 + (size_t)i * HID * HID, conv_b2 + i * HID,
                xres, slice_out, EMB, N);
        } else {
            fused_layer<false><<<gb16, 256, 0, stream>>>(
                emb, i * 16, EMB / 8, row_ptr, csr_src,
                Wt_c1 + (size_t)i * HID * HID, conv_b1 + i * HID,
                Wt_c2 + (size_t)i * HID * HID, conv_b2 + i * HID,
                xres, slice_out, EMB, N);
        }
    }

    pool_all<<<G * 8, 128, 0, stream>>>(emb, gstart, part, EMB);
    pool_fin<<<(G * EMB) / 128, 128, 0, stream>>>(part, pooled, EMB);
    post_mfma<<<1, 256, 0, stream>>>(pooled, w1t, post_b1, w2t, post_b2, outp, EMB);
}